// Round 3
// baseline (9312.318 us; speedup 1.0000x reference)
//
#include <hip/hip_runtime.h>
#include <cstdint>
#include <cstddef>

#define LSEQ 8192
#define NT   34
#define NP   36
#define SCH  64
#define CCH  128
#define F_L2E 1.4426950408889634f
#define F_LN2 0.6931471805599453f

typedef int v4i __attribute__((ext_vector_type(4)));

__device__ __forceinline__ float ex2(float x){ return exp2f(x); }
__device__ __forceinline__ float lg2(float x){ return __log2f(x); }

__device__ __forceinline__ float sigf(float x){
  return __fdividef(1.f, 1.f + ex2(-F_L2E * x));
}
__device__ __forceinline__ float tanhf_fast(float x){
  return 1.f - __fdividef(2.f, ex2(2.f * F_L2E * x) + 1.f);
}

// barrier without the vmcnt(0) drain: LDS-only fence + s_barrier.
__device__ __forceinline__ void barrier_lds(){
  asm volatile("s_waitcnt lgkmcnt(0)\n\ts_barrier" ::: "memory");
}

// ---------------------------------------------------------------------------
// Kernel 1: quantize Whh (both dirs) to int8 per-row. Wq: [dir][row r][64 dw]
// facP permuted: [dir][u*4+g]  (r = g*256+u)
// ---------------------------------------------------------------------------
__global__ void k_quant(const float* __restrict__ Whh_f,
                        const float* __restrict__ Whh_b,
                        int* __restrict__ Wq, float* __restrict__ facP){
  int bid = blockIdx.x;
  int dir = bid >> 10;
  int r   = bid & 1023;
  int i   = threadIdx.x;           // 0..63
  const float* W = (dir ? Whh_b : Whh_f) + r * 256 + i * 4;
  float w0 = W[0], w1 = W[1], w2 = W[2], w3 = W[3];
  float m = fmaxf(fmaxf(fabsf(w0), fabsf(w1)), fmaxf(fabsf(w2), fabsf(w3)));
  for (int s = 32; s; s >>= 1) m = fmaxf(m, __shfl_xor(m, s));
  float scale = (m > 0.f) ? m / 127.f : 1.f;
  float inv = __fdividef(1.f, scale);
  int q0 = (int)rintf(w0 * inv), q1 = (int)rintf(w1 * inv);
  int q2 = (int)rintf(w2 * inv), q3 = (int)rintf(w3 * inv);
  q0 = max(-127, min(127, q0)); q1 = max(-127, min(127, q1));
  q2 = max(-127, min(127, q2)); q3 = max(-127, min(127, q3));
  int p = (q0 & 255) | ((q1 & 255) << 8) | ((q2 & 255) << 16) | ((q3 & 255) << 24);
  Wq[(dir << 16) + (r << 6) + i] = p;
  if (i == 0) {
    int g = r >> 8, u = r & 255;
    facP[(dir << 10) + u * 4 + g] = scale * (1.f / 127.f);
  }
}

// ---------------------------------------------------------------------------
// Kernel 2: G'[t][u*4+g] = b[g*256+u] + sum_e x[t][e] * Wih[g*256+u][e]
// Permuted gate-interleaved layout, coalesced float4 stores.
// grid (512, 2) x 256 threads; 16 timesteps per block, 2 passes of 8.
// ---------------------------------------------------------------------------
__global__ void k_gproj(const int* __restrict__ words,
                        const float* __restrict__ embed,
                        const float* __restrict__ Wih_f, const float* __restrict__ b_f,
                        const float* __restrict__ Wih_b, const float* __restrict__ b_b,
                        float* __restrict__ G_f, float* __restrict__ G_b){
  int dir = blockIdx.y;
  const float* Wih = dir ? Wih_b : Wih_f;
  const float* bb  = dir ? b_b  : b_f;
  float* G = dir ? G_b : G_f;
  int t0 = blockIdx.x * 16;
  int uu = threadIdx.x;            // unit 0..255
  __shared__ __align__(16) float X[16 * 256];
  for (int idx = threadIdx.x; idx < 16 * 256; idx += 256) {
    int tt = idx >> 8, e = idx & 255;
    X[idx] = embed[(size_t)words[t0 + tt] * 256 + e];
  }
  __syncthreads();
  const float4* X4 = (const float4*)X;
  const float4* Wr0 = (const float4*)(Wih + (size_t)(uu)       * 256);
  const float4* Wr1 = (const float4*)(Wih + (size_t)(uu + 256) * 256);
  const float4* Wr2 = (const float4*)(Wih + (size_t)(uu + 512) * 256);
  const float4* Wr3 = (const float4*)(Wih + (size_t)(uu + 768) * 256);
  float b0 = bb[uu], b1 = bb[uu + 256], b2 = bb[uu + 512], b3 = bb[uu + 768];
  for (int pass = 0; pass < 2; pass++) {
    float4 acc[8];
#pragma unroll
    for (int tt = 0; tt < 8; tt++) acc[tt] = make_float4(b0, b1, b2, b3);
    for (int eb = 0; eb < 64; eb++) {
      float4 w0 = Wr0[eb], w1 = Wr1[eb], w2 = Wr2[eb], w3 = Wr3[eb];
#pragma unroll
      for (int tt = 0; tt < 8; tt++) {
        float4 x = X4[(pass * 8 + tt) * 64 + eb];
        acc[tt].x += w0.x * x.x + w0.y * x.y + w0.z * x.z + w0.w * x.w;
        acc[tt].y += w1.x * x.x + w1.y * x.y + w1.z * x.z + w1.w * x.w;
        acc[tt].z += w2.x * x.x + w2.y * x.y + w2.z * x.z + w2.w * x.w;
        acc[tt].w += w3.x * x.x + w3.y * x.y + w3.z * x.z + w3.w * x.w;
      }
    }
#pragma unroll
    for (int tt = 0; tt < 8; tt++)
      *(float4*)(G + (size_t)(t0 + pass * 8 + tt) * 1024 + uu * 4) = acc[tt];
  }
}

// ---------------------------------------------------------------------------
// Kernel 3: LSTM recurrence via i8 MFMA. block 0 = fwd, block 1 = bwd.
// 512 threads = 8 waves; wave w owns units w*32..w*32+31.
// Row permutation: tile T (of 8), tile-row (q*4+g) = gate g of unit
// u = w*32 + T*4 + q.  Lane L: m=L&15 (A row), q=L>>4, T=L&7.
// C layout (16x16): col=lane&15, row=q*4+reg  ->  reg = gate g of unit
// u(w, T, q).  Gate math thread-local; ONE lgkm-barrier/step; h8 dbuf.
// ---------------------------------------------------------------------------
__global__ __launch_bounds__(512, 2) void k_lstm3(const int* __restrict__ Wq,
                                                  const float* __restrict__ facP,
                                                  const float* __restrict__ G_f,
                                                  const float* __restrict__ G_b,
                                                  float* __restrict__ hf,
                                                  float* __restrict__ hb){
  int dir = blockIdx.x;
  const int* Wqd = Wq + (dir << 16);
  const float* G = dir ? G_b : G_f;
  float* hout = dir ? hb : hf;
  int tid = threadIdx.x;
  int w = tid >> 6, L = tid & 63;
  int m = L & 15, q = L >> 4, T = L & 7, col = L & 15;
  int u = w * 32 + T * 4 + q;

  __shared__ int h8[2 * 64];       // two 256-byte int8 h buffers

  // A fragments: 8 tiles x 4 K-blocks, 16 int8 each = 128 VGPRs
  v4i afr[8][4];
#pragma unroll
  for (int t8 = 0; t8 < 8; t8++) {
    int r_orig = (m & 3) * 256 + (w * 32 + t8 * 4 + (m >> 2));
    const int* base = Wqd + r_orig * 64;
#pragma unroll
    for (int kt = 0; kt < 4; kt++) {
      int4 tmp = *(const int4*)(base + kt * 16 + q * 4);
      afr[t8][kt] = (v4i){tmp.x, tmp.y, tmp.z, tmp.w};
    }
  }
  float4 fv = *(const float4*)(facP + (dir << 10) + u * 4);
  int time0 = dir ? 8191 : 0;
  float4 gcur = *(const float4*)(G + (size_t)time0 * 1024 + u * 4);

  if (tid < 128) h8[tid] = 0;
  float c = 0.f;
  __syncthreads();

  for (int t = 0; t < 8192; t++) {
    int tn = (t + 1 < 8192) ? t + 1 : 8191;
    int time_n = dir ? (8191 - tn) : tn;
    float4 gnext = *(const float4*)(G + (size_t)time_n * 1024 + u * 4);

    int p = t & 1;
    const char* rb = (const char*)h8 + p * 256;
    v4i bfr[4];
#pragma unroll
    for (int kt = 0; kt < 4; kt++) {
      int4 tmp = *(const int4*)(rb + kt * 64 + q * 16);
      bfr[kt] = (v4i){tmp.x, tmp.y, tmp.z, tmp.w};
    }
    v4i acc[8];
#pragma unroll
    for (int t8 = 0; t8 < 8; t8++) {
      v4i a = (v4i){0, 0, 0, 0};
#pragma unroll
      for (int kt = 0; kt < 4; kt++)
        a = __builtin_amdgcn_mfma_i32_16x16x64_i8(afr[t8][kt], bfr[kt], a, 0, 0, 0);
      acc[t8] = a;
    }
    // select acc[T] (runtime T) via cndmask tree
    v4i x0 = (T & 1) ? acc[1] : acc[0];
    v4i x1 = (T & 1) ? acc[3] : acc[2];
    v4i x2 = (T & 1) ? acc[5] : acc[4];
    v4i x3 = (T & 1) ? acc[7] : acc[6];
    v4i y0 = (T & 2) ? x1 : x0;
    v4i y1 = (T & 2) ? x3 : x2;
    v4i d  = (T & 4) ? y1 : y0;

    float ri = (float)d[0] * fv.x + gcur.x;
    float rf = (float)d[1] * fv.y + gcur.y;
    float rg = (float)d[2] * fv.z + gcur.z;
    float ro = (float)d[3] * fv.w + gcur.w;
    float is = sigf(ri), fs = sigf(rf);
    float gt = tanhf_fast(rg), os = sigf(ro);
    c = fs * c + is * gt;
    float h = os * tanhf_fast(c);

    int time = dir ? (8191 - t) : t;
    if (col < 8) {   // col == T here: exactly one writer per unit
      hout[(size_t)time * 256 + u] = h;
      ((signed char*)h8)[(p ^ 1) * 256 + u] = (signed char)(int)rintf(h * 127.f);
    }
    gcur = gnext;
    barrier_lds();
  }
}

// ---------------------------------------------------------------------------
// Kernel 4: feats = [hf | hb] @ W_out.T + b_out.
// ---------------------------------------------------------------------------
__global__ void k_feats(const float* __restrict__ hf, const float* __restrict__ hb,
                        const float* __restrict__ W_out, const float* __restrict__ b_out,
                        float* __restrict__ feats){
  int t0 = blockIdx.x * 16;
  for (int oi = threadIdx.x; oi < 16 * NT; oi += 256) {
    int tt = oi / NT;
    int tag = oi - tt * NT;
    int t = t0 + tt;
    const float4* w4 = (const float4*)(W_out + (size_t)tag * 512);
    const float4* a4 = (const float4*)(hf + (size_t)t * 256);
    const float4* c4 = (const float4*)(hb + (size_t)t * 256);
    float acc = b_out[tag];
    for (int k = 0; k < 64; k++) {
      float4 w = w4[k]; float4 h = a4[k];
      acc += w.x * h.x + w.y * h.y + w.z * h.z + w.w * h.w;
    }
    for (int k = 0; k < 64; k++) {
      float4 w = w4[64 + k]; float4 h = c4[k];
      acc += w.x * h.x + w.y * h.y + w.z * h.z + w.w * h.w;
    }
    feats[(size_t)t * NT + tag] = acc;
  }
}

// ---------------------------------------------------------------------------
// CRF chunked associative scan, (lse,+) semiring, log2-domain (r2, unchanged).
// ---------------------------------------------------------------------------
__global__ __launch_bounds__(320) void k_crf_p1(const float* __restrict__ feats,
                                                const float* __restrict__ trans,
                                                float* __restrict__ Pg,
                                                float* __restrict__ rmaxG){
  int dir = blockIdx.x >> 7;
  int c   = blockIdx.x & (CCH - 1);
  int tid = threadIdx.x;
  int t0  = c * SCH;

  __shared__ __align__(16) float TRM[NT * NP];
  __shared__ float Fe[(SCH + 1) * NT];
  __shared__ __align__(16) float Pbuf[2][NT * NP];
  __shared__ float CM[NP];
  __shared__ float RMs[NT];

  for (int idx = tid; idx < NT * NT; idx += 320) {
    int j = idx / NT, k = idx - j * NT;
    float v = (dir == 0) ? trans[j * NT + k] : trans[k * NT + j];
    TRM[j * NP + k] = v * F_L2E;
  }
  for (int idx = tid; idx < (SCH + 1) * NT; idx += 320) {
    int s = idx / NT, j = idx - s * NT;
    int t = t0 + s; if (t > LSEQ - 1) t = LSEQ - 1;
    Fe[idx] = feats[(size_t)t * NT + j] * F_L2E;
  }
  for (int idx = tid; idx < NT * NP; idx += 320) {
    int k = idx / NP, i = idx - k * NP;
    Pbuf[0][idx] = (i < NT && i == k) ? 0.f : -1e30f;
  }
  if (tid < NP) CM[tid] = (tid < NT) ? 0.f : -1e30f;
  __syncthreads();
  if (tid < NT) {
    float m = -3e38f;
    for (int k = 0; k < NT; k++) m = fmaxf(m, TRM[tid * NP + k]);
    RMs[tid] = m;
  }
  __syncthreads();
  for (int idx = tid; idx < NT * NT; idx += 320) {
    int j = idx / NT, k = idx - j * NT;
    TRM[j * NP + k] -= RMs[j];
  }
  __syncthreads();

  int cur = 0;
  int j = tid / 9, g = tid - (tid / 9) * 9;
  bool act = (tid < 306);
  int i0 = 4 * g;

  for (int s = 0; s < SCH; s++) {
    int t = (dir == 0) ? (t0 + s) : (t0 + SCH - 1 - s);
    if (dir == 1 && t == LSEQ - 1) continue;   // identity factor at t=L-1
    const float* Pc = Pbuf[cur];
    float* Pn = Pbuf[cur ^ 1];
    if (act) {
      float cm0 = CM[i0], cm1 = CM[i0 + 1], cm2 = CM[i0 + 2], cm3 = CM[i0 + 3];
      float s0 = 0, s1 = 0, s2 = 0, s3 = 0;
      const float* trp = TRM + j * NP;
      const float* fep = Fe + (t + 1 - t0) * NT;
#pragma unroll
      for (int k = 0; k < NT; k++) {
        float trv = trp[k];
        if (dir == 1) trv += fep[k];
        float4 p = *(const float4*)&Pc[k * NP + i0];
        s0 += ex2(trv + p.x - cm0);
        s1 += ex2(trv + p.y - cm1);
        s2 += ex2(trv + p.z - cm2);
        s3 += ex2(trv + p.w - cm3);
      }
      float base = RMs[j] + ((dir == 0) ? Fe[(t - t0) * NT + j] : 0.f);
      float4 o;
      o.x = base + cm0 + lg2(s0);
      o.y = base + cm1 + lg2(s1);
      o.z = (i0 + 2 < NT) ? (base + cm2 + lg2(s2)) : -1e30f;
      o.w = (i0 + 3 < NT) ? (base + cm3 + lg2(s3)) : -1e30f;
      *(float4*)&Pn[j * NP + i0] = o;
    }
    __syncthreads();
    if (tid < NP) {
      float m = -3e38f;
      const float* colp = Pn + tid;
      for (int k = 0; k < NT; k++) m = fmaxf(m, colp[k * NP]);
      CM[tid] = m;
    }
    cur ^= 1;
    __syncthreads();
  }

  const float* Pf = Pbuf[cur];
  size_t base = (size_t)((dir << 7) + c) * (NT * NP);
  for (int idx = tid; idx < NT * NP; idx += 320)
    Pg[base + idx] = Pf[idx];
  if (tid < NT) {
    float m = -3e38f;
    for (int i = 0; i < NT; i++) m = fmaxf(m, Pf[tid * NP + i]);
    rmaxG[((dir << 7) + c) * NT + tid] = m;
  }
}

__global__ void k_crf_p2(const float* __restrict__ trans,
                         const float* __restrict__ Pg,
                         const float* __restrict__ rmaxG,
                         float* __restrict__ vIn){
  int dir = blockIdx.x;
  int lane = threadIdx.x;           // 64, single wave
  bool a = (lane < NT);
  int j = a ? lane : 0;
  __shared__ float V[NP];

  float v;
  if (dir == 0) {
    v = (lane == 32) ? 0.f : -10000.f * F_L2E;
  } else {
    float m = -3e38f;
    for (int i = 0; i < NT; i++) m = fmaxf(m, trans[i * NT + j]);
    float s = 0.f;
    for (int i = 0; i < NT; i++) s += ex2((trans[i * NT + j] - m) * F_L2E);
    v = m * F_L2E + lg2(s);
  }
  if (lane < NP) V[lane] = -1e30f;
  barrier_lds();
  if (a) V[j] = v;
  barrier_lds();
  float vm = a ? v : -3e38f;
  for (int off = 32; off; off >>= 1) vm = fmaxf(vm, __shfl_xor(vm, off));

  if (a) {
    int c0 = (dir == 0) ? 0 : (CCH - 1);
    vIn[((size_t)(dir << 7) + c0) * NP + j] = v;
  }

  for (int it = 0; it < CCH - 1; it++) {
    int c = (dir == 0) ? it : (CCH - 1 - it);
    const float* row = Pg + ((size_t)(dir << 7) + c) * (NT * NP) + j * NP;
    float rm = rmaxG[((dir << 7) + c) * NT + j];
    float m = rm + vm;
    float s = 0.f;
#pragma unroll
    for (int k = 0; k < NP; k += 4) {
      float4 p = *(const float4*)&row[k];
      s += ex2(p.x + V[k]     - m);
      s += ex2(p.y + V[k + 1] - m);
      s += ex2(p.z + V[k + 2] - m);
      s += ex2(p.w + V[k + 3] - m);
    }
    float nv = m + lg2(s);
    if (a) V[j] = nv;
    barrier_lds();
    float x = a ? nv : -3e38f;
    for (int off = 32; off; off >>= 1) x = fmaxf(x, __shfl_xor(x, off));
    vm = x;
    int cn = (dir == 0) ? (c + 1) : (c - 1);
    if (a) vIn[((size_t)(dir << 7) + cn) * NP + j] = nv;
  }
}

__global__ void k_crf_p3(const float* __restrict__ feats,
                         const float* __restrict__ trans,
                         const float* __restrict__ vIn,
                         float* __restrict__ wsA,
                         float* __restrict__ wsB){
  int dir = blockIdx.x >> 7;
  int c   = blockIdx.x & (CCH - 1);
  int lane = threadIdx.x;           // 64, single wave
  int t0 = c * SCH;
  bool a = (lane < NT);
  int j = a ? lane : 0;
  __shared__ float A[NP];
  __shared__ float U[NP];

  float trr[NT];
  float rm = -3e38f;
#pragma unroll
  for (int k = 0; k < NT; k++) {
    float vv = (dir == 0) ? trans[j * NT + k] : trans[k * NT + j];
    trr[k] = vv * F_L2E;
    rm = fmaxf(rm, trr[k]);
  }
  if (lane < NP) { A[lane] = -1e30f; U[lane] = -1e30f; }
  float v0 = vIn[((size_t)(dir << 7) + c) * NP + j];
  barrier_lds();
  if (a) A[j] = v0;
  barrier_lds();
  float am = a ? v0 : -3e38f;
  for (int off = 32; off; off >>= 1) am = fmaxf(am, __shfl_xor(am, off));

  if (dir == 0) {
    float fe = feats[(size_t)t0 * NT + j] * F_L2E;
    for (int s = 0; s < SCH; s++) {
      int t = t0 + s;
      int tn = (t + 1 < LSEQ) ? t + 1 : LSEQ - 1;
      float fe_n = feats[(size_t)tn * NT + j] * F_L2E;
      float m = rm + am;
      float ss = 0.f;
#pragma unroll
      for (int k = 0; k < NT; k++) ss += ex2(trr[k] + A[k] - m);
      float out = m + lg2(ss) + fe;
      if (a) wsA[(size_t)t * NT + j] = out * F_LN2;
      if (a) A[j] = out;
      barrier_lds();
      float x = a ? out : -3e38f;
      for (int off = 32; off; off >>= 1) x = fmaxf(x, __shfl_xor(x, off));
      am = x;
      fe = fe_n;
    }
  } else {
    float b = v0;
    int tfirst = t0 + SCH; if (tfirst > LSEQ - 1) tfirst = LSEQ - 1;
    float fe = feats[(size_t)tfirst * NT + j] * F_L2E;
    for (int s = 0; s < SCH; s++) {
      int t = t0 + SCH - 1 - s;
      float fe_n = feats[(size_t)t * NT + j] * F_L2E;
      float out;
      if (t == LSEQ - 1) {
        out = b;
      } else {
        if (a) U[j] = b + fe;
        barrier_lds();
        float um = a ? U[j] : -3e38f;
        for (int off = 32; off; off >>= 1) um = fmaxf(um, __shfl_xor(um, off));
        float m = rm + um;
        float ss = 0.f;
#pragma unroll
        for (int k = 0; k < NT; k++) ss += ex2(trr[k] + U[k] - m);
        out = m + lg2(ss);
        barrier_lds();
      }
      if (a) wsB[(size_t)t * NT + j] = out * F_LN2;
      b = out;
      fe = fe_n;
    }
  }
}

// ---------------------------------------------------------------------------
__global__ void k_finish(const float* __restrict__ wsA, const float* __restrict__ wsB,
                         float* __restrict__ out){
  int t = blockIdx.x * 256 + threadIdx.x;
  float m = -3e38f; int bi = 0;
  for (int i = 0; i < NT; i++) {
    float sc = wsA[(size_t)t * NT + i] + wsB[(size_t)t * NT + i];
    out[(size_t)t * NT + i] = sc;
    if (sc > m) { m = sc; bi = i; }
  }
  out[(size_t)LSEQ * NT + t] = (float)bi;
}

// ---------------------------------------------------------------------------
extern "C" void kernel_launch(void* const* d_in, const int* in_sizes, int n_in,
                              void* d_out, int out_size, void* d_ws, size_t ws_size,
                              hipStream_t stream) {
  const int*   words  = (const int*)  d_in[0];
  const float* embed  = (const float*)d_in[1];
  const float* Wih_f  = (const float*)d_in[2];
  const float* Whh_f  = (const float*)d_in[3];
  const float* b_f    = (const float*)d_in[4];
  const float* Wih_b  = (const float*)d_in[5];
  const float* Whh_b  = (const float*)d_in[6];
  const float* b_b    = (const float*)d_in[7];
  const float* W_out  = (const float*)d_in[8];
  const float* b_out  = (const float*)d_in[9];
  const float* trans  = (const float*)d_in[10];
  float* out = (float*)d_out;

  float* wsf = (float*)d_ws;
  size_t off = 0;
  float* G_f   = wsf + off; off += (size_t)LSEQ * 1024;
  float* G_b   = wsf + off; off += (size_t)LSEQ * 1024;
  float* hf    = wsf + off; off += (size_t)LSEQ * 256;
  float* hb    = wsf + off; off += (size_t)LSEQ * 256;
  float* feats = wsf + off; off += (size_t)LSEQ * NT + 16;
  float* wsA   = wsf + off; off += (size_t)LSEQ * NT + 16;
  float* wsB   = wsf + off; off += (size_t)LSEQ * NT + 16;
  float* facP  = wsf + off; off += 2048;
  int*   Wq    = (int*)(wsf + off); off += 2 * 1024 * 64;
  // CRF scan scratch overlaps G_f (dead after k_lstm3)
  float* Pg    = G_f;
  float* rmaxG = G_f + 256 * (NT * NP);
  float* vIn   = rmaxG + 256 * NT + 32;

  k_quant<<<2048, 64, 0, stream>>>(Whh_f, Whh_b, Wq, facP);
  k_gproj<<<dim3(512, 2), 256, 0, stream>>>(words, embed, Wih_f, b_f, Wih_b, b_b, G_f, G_b);
  k_lstm3<<<2, 512, 0, stream>>>(Wq, facP, G_f, G_b, hf, hb);
  k_feats<<<512, 256, 0, stream>>>(hf, hb, W_out, b_out, feats);
  k_crf_p1<<<256, 320, 0, stream>>>(feats, trans, Pg, rmaxG);
  k_crf_p2<<<2, 64, 0, stream>>>(trans, Pg, rmaxG, vIn);
  k_crf_p3<<<256, 64, 0, stream>>>(feats, trans, vIn, wsA, wsB);
  k_finish<<<32, 256, 0, stream>>>(wsA, wsB, out);
}